// Round 5
// baseline (451.201 us; speedup 1.0000x reference)
//
#include <hip/hip_runtime.h>
#include <hip/hip_bf16.h>
#include <math.h>

#define NN 8192
#define DD 256
#define FF 64
#define NSPLIT 8
#define JCHUNK (NN / NSPLIT)  // 1024
#define CT 128                // j columns staged per round
#define NT (JCHUNK / CT)      // 8

typedef __attribute__((ext_vector_type(8))) short bf16x8;
typedef __attribute__((ext_vector_type(4))) float f32x4;

__device__ __forceinline__ float lrelu(float x) { return fmaxf(x, 0.2f * x); }
__device__ __forceinline__ ushort f2bf(float x) {
  union { __hip_bfloat16 b; ushort s; } u;
  u.b = __float2bfloat16(x);
  return u.s;
}
__device__ __forceinline__ float bf2f(ushort s) {
  union { uint u; float f; } v;
  v.u = (uint)s << 16;
  return v.f;
}

// ---------------------------------------------------------------------------
// k_pre: W [256][64] f32 -> WT [64][256] bf16.
// ---------------------------------------------------------------------------
__global__ __launch_bounds__(256) void k_pre(const float* __restrict__ W,
                                             ushort* __restrict__ WT) {
  const int e4 = (blockIdx.x * 256 + threadIdx.x) * 4;  // element = k*64 + d
  const float4 wv = *(const float4*)(W + e4);
  const int k = e4 >> 6, d = e4 & 63;
  WT[(d + 0) * DD + k] = f2bf(wv.x);
  WT[(d + 1) * DD + k] = f2bf(wv.y);
  WT[(d + 2) * DD + k] = f2bf(wv.z);
  WT[(d + 3) * DD + k] = f2bf(wv.w);
}

// ---------------------------------------------------------------------------
// k_mask: adj (int32 0/1, 268 MB) -> bitmask (8 MB). Pure streaming kernel.
// Lane-consecutive int4 loads (16B/lane, 1KB/wave-instr); nibble per lane,
// shfl-tree assembles dwords; bit j of dword m == adj j = 32m + bit.
// ---------------------------------------------------------------------------
__global__ __launch_bounds__(256) void k_mask(const int* __restrict__ adj,
                                              uint* __restrict__ mask) {
  const size_t nquad = (size_t)NN * NN / 4;
  const size_t stride = (size_t)gridDim.x * 256;
  const int lane = threadIdx.x & 63;
  for (size_t q = (size_t)blockIdx.x * 256 + threadIdx.x; q < nquad; q += stride) {
    const int4 v = ((const int4*)adj)[q];
    uint nib = (uint)(v.x & 1) | ((uint)(v.y & 1) << 1) |
               ((uint)(v.z & 1) << 2) | ((uint)(v.w & 1) << 3);
    uint b = nib | ((uint)__shfl_xor((int)nib, 1) << 4);   // byte @ even lanes
    b |= (uint)__shfl_xor((int)b, 2) << 8;                 // 16b @ lanes%4==0
    b |= (uint)__shfl_xor((int)b, 4) << 16;                // 32b @ lanes%8==0
    if ((lane & 7) == 0) mask[q >> 3] = b;
  }
}

// ---------------------------------------------------------------------------
// k_h: h = feat @ W via MFMA (verified rounds 3-4). Wave w = d-slab
// [w*16,w*16+16). hTf stored in MFMA fragment order:
// hTf[((f*256 + j32)*64 + kg*16 + il)*8 + e] = hT[f*16+il][j32*32 + kg*8 + e].
// Also s1 = h@a1, s2 = h@a2 from f32 accumulators.
// ---------------------------------------------------------------------------
__global__ __launch_bounds__(256) void k_h(
    const float* __restrict__ feat, const ushort* __restrict__ WT,
    const float* __restrict__ a, ushort* __restrict__ hTf,
    float* __restrict__ s1, float* __restrict__ s2) {
  __shared__ float sp1[4][16], sp2[4][16];
  const int t = threadIdx.x, lane = t & 63, w = t >> 6;
  const int il = lane & 15, kg = lane >> 4;
  const int ibase = blockIdx.x * 16;
  const int d = w * 16 + il;
  const float* frow = feat + (size_t)(ibase + il) * DD + kg * 8;
  const ushort* wrow = WT + (size_t)d * DD + kg * 8;
  f32x4 acc = {0.f, 0.f, 0.f, 0.f};
#pragma unroll
  for (int k0 = 0; k0 < DD; k0 += 32) {
    const float4 fa = *(const float4*)(frow + k0);
    const float4 fb = *(const float4*)(frow + k0 + 4);
    bf16x8 av;
    av[0] = f2bf(fa.x); av[1] = f2bf(fa.y); av[2] = f2bf(fa.z); av[3] = f2bf(fa.w);
    av[4] = f2bf(fb.x); av[5] = f2bf(fb.y); av[6] = f2bf(fb.z); av[7] = f2bf(fb.w);
    const bf16x8 bv = *(const bf16x8*)(wrow + k0);
    acc = __builtin_amdgcn_mfma_f32_16x16x32_bf16(av, bv, acc, 0, 0, 0);
  }
  ushort4 hv;
  hv.x = f2bf(acc[0]);
  hv.y = f2bf(acc[1]);
  hv.z = f2bf(acc[2]);
  hv.w = f2bf(acc[3]);
  {
    const int i0q = ibase + kg * 4;  // 4-aligned j-index
    const size_t hb = ((size_t)(w * 256 + (i0q >> 5)) * 64 +
                       ((i0q >> 3) & 3) * 16 + il) * 8 + (i0q & 7);
    *(ushort4*)(hTf + hb) = hv;
  }
  const float a1v = a[d], a2v = a[FF + d];
#pragma unroll
  for (int r = 0; r < 4; ++r) {
    float v1 = acc[r] * a1v;
    float v2 = acc[r] * a2v;
#pragma unroll
    for (int m = 1; m <= 8; m <<= 1) {
      v1 += __shfl_xor(v1, m);
      v2 += __shfl_xor(v2, m);
    }
    if (il == 0) {
      sp1[w][kg * 4 + r] = v1;
      sp2[w][kg * 4 + r] = v2;
    }
  }
  __syncthreads();
  if (t < 16) {
    s1[ibase + t] = sp1[0][t] + sp1[1][t] + sp1[2][t] + sp1[3][t];
    s2[ibase + t] = sp2[0][t] + sp2[1][t] + sp2[2][t] + sp2[3][t];
  }
}

// ---------------------------------------------------------------------------
// k_attn: fused mask+exp+PV from the 8 MB bitmask (HBM-light).
// Grid 1024 = 128 i-groups x 8 j-splits; per wave 16 rows x 1024 j, zero
// barriers (wave-private swizzled LDS p-tiles). Structure verified round 4;
// only the adjacency source changed (int4 loads -> broadcast dword + nibble).
// ---------------------------------------------------------------------------
__global__ __launch_bounds__(256) void k_attn(
    const uint* __restrict__ mask, const ushort* __restrict__ hTf,
    const float* __restrict__ s1g, const float* __restrict__ s2g,
    float* __restrict__ pacc, float* __restrict__ pl) {
  __shared__ __align__(16) char smem[4][4480];
  __shared__ float s1w[4][16];
  const int t = threadIdx.x;
  const int lane = t & 63, w = t >> 6;
  const int il = lane & 15, kg = lane >> 4;
  const int ig = blockIdx.x >> 3, js = blockIdx.x & 7;
  const int rbase = ig * 64 + w * 16;
  const int jwin0 = js * JCHUNK;
  char* const smemw = smem[w];

  if (lane < 16) s1w[w][lane] = s1g[rbase + lane];  // same-wave LDS, no barrier
  const int arow = lane >> 5;        // which of 2 rows per rep
  const int acol = (lane & 31) * 4;  // 4 consecutive j per lane
  const int nsh = (lane & 7) * 4;    // nibble shift within mask dword
  const uint* mrow = mask + (size_t)(rbase + arow) * (NN / 32) + (jwin0 >> 5) +
                     ((lane & 31) >> 3);

  float lacc = 0.f;
  f32x4 acc[4] = {{0,0,0,0},{0,0,0,0},{0,0,0,0},{0,0,0,0}};

  for (int tile = 0; tile < NT; ++tile) {
    const int jt = jwin0 + tile * CT;
    // ---- Phase A: p from bitmask, lane<->j, swizzled LDS bf16 tile ----
    const float4 s2v = *(const float4*)(s2g + jt + acol);
#pragma unroll
    for (int rep = 0; rep < 8; ++rep) {
      const int r = rep * 2 + arow;
      const uint mv = mrow[(size_t)(rep * 2) * (NN / 32) + tile * (CT / 32)];
      const uint nib = (mv >> nsh) & 0xfu;
      const float s1v = s1w[w][r];
      const float mi = lrelu(s1v + 8.0f);
      ushort4 pk;
      pk.x = (nib & 1u) ? f2bf(__expf(lrelu(s1v + s2v.x) - mi)) : (ushort)0;
      pk.y = (nib & 2u) ? f2bf(__expf(lrelu(s1v + s2v.y) - mi)) : (ushort)0;
      pk.z = (nib & 4u) ? f2bf(__expf(lrelu(s1v + s2v.z) - mi)) : (ushort)0;
      pk.w = (nib & 8u) ? f2bf(__expf(lrelu(s1v + s2v.w) - mi)) : (ushort)0;
      const int swz = r * 256 + ((acol * 2) ^ ((r & 7) << 4));
      *(ushort4*)(smemw + swz) = pk;
    }
    // ---- Phase B: ds_read B-frags (swizzle-matched), hTf A-frags, MFMA ----
#pragma unroll
    for (int sb = 0; sb < 4; ++sb) {
      const int coff = (sb * 32 + kg * 8) * 2;
      const bf16x8 pb = *(const bf16x8*)(smemw + il * 256 + (coff ^ ((il & 7) << 4)));
      float ps = 0.f;
#pragma unroll
      for (int e = 0; e < 8; ++e) ps += bf2f((ushort)pb[e]);
      lacc += ps;
      const int j32 = (jt >> 5) + sb;
#pragma unroll
      for (int f = 0; f < 4; ++f) {
        const bf16x8 hvv =
            *(const bf16x8*)(hTf + ((size_t)(f * 256 + j32) * 64 + lane) * 8);
        acc[f] = __builtin_amdgcn_mfma_f32_16x16x32_bf16(hvv, pb, acc[f], 0, 0, 0);
      }
    }
  }
  // l: lane (il,kg) holds row il's partial over its kg j-subset
  lacc += __shfl_xor(lacc, 16);
  lacc += __shfl_xor(lacc, 32);
  if (lane < 16) pl[(size_t)js * NN + rbase + lane] = lacc;
  // C/D: lane holds i = rbase + il (col), d = f*16 + kg*4 + r (row)
  float (*tr)[65] = (float(*)[65])smemw;
#pragma unroll
  for (int f = 0; f < 4; ++f)
#pragma unroll
    for (int r = 0; r < 4; ++r) tr[il][f * 16 + kg * 4 + r] = acc[f][r];
#pragma unroll
  for (int r = 0; r < 16; ++r)
    pacc[((size_t)js * NN + rbase + r) * FF + lane] = tr[r][lane];
}

// ---------------------------------------------------------------------------
// k_combine: sum partials, normalize, ELU. Fully coalesced.
// ---------------------------------------------------------------------------
__global__ __launch_bounds__(256) void k_combine(
    const float* __restrict__ pacc, const float* __restrict__ pl,
    float* __restrict__ out) {
  const int idx = blockIdx.x * 256 + threadIdx.x;
  const int i = idx >> 6;
  float s = 0.f, L = 0.f;
#pragma unroll
  for (int sp = 0; sp < NSPLIT; ++sp) {
    s += pacc[(size_t)sp * NN * FF + idx];
    L += pl[(size_t)sp * NN + i];
  }
  float x = s / fmaxf(L, 1e-30f);
  out[idx] = x > 0.f ? x : expm1f(x);
}

extern "C" void kernel_launch(void* const* d_in, const int* in_sizes, int n_in,
                              void* d_out, int out_size, void* d_ws, size_t ws_size,
                              hipStream_t stream) {
  const float* feat = (const float*)d_in[0];
  const int* adj = (const int*)d_in[1];
  const float* W = (const float*)d_in[2];
  const float* a = (const float*)d_in[3];
  float* out = (float*)d_out;

  ushort* hTf = (ushort*)d_ws;                      // 64*8192 bf16 = 1 MB
  ushort* WT = hTf + (size_t)FF * NN;               // 64*256 bf16 = 32 KB
  float* s1 = (float*)(WT + (size_t)FF * DD);       // 8192 f32
  float* s2 = s1 + NN;                              // 8192 f32
  float* pl = s2 + NN;                              // NSPLIT*8192 f32
  float* pacc = pl + (size_t)NSPLIT * NN;           // NSPLIT*8192*64 f32 (16.7 MB)
  uint* mask = (uint*)(pacc + (size_t)NSPLIT * NN * FF);  // 8 MB bitmask

  hipLaunchKernelGGL(k_pre, dim3(DD * FF / 1024), dim3(256), 0, stream, W, WT);
  hipLaunchKernelGGL(k_h, dim3(NN / 16), dim3(256), 0, stream, feat, WT, a, hTf, s1, s2);
  hipLaunchKernelGGL(k_mask, dim3(2048), dim3(256), 0, stream, adj, mask);
  hipLaunchKernelGGL(k_attn, dim3((NN / 64) * NSPLIT), dim3(256), 0, stream,
                     mask, hTf, s1, s2, pacc, pl);
  hipLaunchKernelGGL(k_combine, dim3(NN * FF / 256), dim3(256), 0, stream,
                     pacc, pl, out);
}

// Round 6
// 436.073 us; speedup vs baseline: 1.0347x; 1.0347x over previous
//
#include <hip/hip_runtime.h>
#include <hip/hip_bf16.h>
#include <math.h>

#define NN 8192
#define DD 256
#define FF 64
#define WPB 8             // waves per k_attn block
#define ROWS 16           // i-rows per k_attn block
#define JW (NN / WPB)     // 1024 j per wave
#define CT 128            // j columns staged per tile
#define NT (JW / CT)      // 8

typedef __attribute__((ext_vector_type(8))) short bf16x8;
typedef __attribute__((ext_vector_type(4))) float f32x4;

__device__ __forceinline__ ushort f2bf(float x) {
  union { __hip_bfloat16 b; ushort s; } u;
  u.b = __float2bfloat16(x);
  return u.s;
}

// ---------------------------------------------------------------------------
// k_pre: W [256][64] f32 -> WT [64][256] bf16.
// ---------------------------------------------------------------------------
__global__ __launch_bounds__(256) void k_pre(const float* __restrict__ W,
                                             ushort* __restrict__ WT) {
  const int e4 = (blockIdx.x * 256 + threadIdx.x) * 4;  // element = k*64 + d
  const float4 wv = *(const float4*)(W + e4);
  const int k = e4 >> 6, d = e4 & 63;
  WT[(d + 0) * DD + k] = f2bf(wv.x);
  WT[(d + 1) * DD + k] = f2bf(wv.y);
  WT[(d + 2) * DD + k] = f2bf(wv.z);
  WT[(d + 3) * DD + k] = f2bf(wv.w);
}

// ---------------------------------------------------------------------------
// k_h: h = feat @ W via MFMA (verified rounds 3-5). Wave w = d-slab
// [w*16,w*16+16). hTf stored in MFMA fragment order:
// hTf[((f*256 + j32)*64 + kg*16 + il)*8 + e] = hT[f*16+il][j32*32 + kg*8 + e].
// Epilogue now stores the exp-factor tables E1=exp(s1), F1=exp(.2 s1),
// E2=exp(s2), F2=exp(.2 s2)  (s1 = h@a1, s2 = h@a2 from f32 accumulators).
// ---------------------------------------------------------------------------
__global__ __launch_bounds__(256) void k_h(
    const float* __restrict__ feat, const ushort* __restrict__ WT,
    const float* __restrict__ a, ushort* __restrict__ hTf,
    float* __restrict__ E1, float* __restrict__ F1,
    float* __restrict__ E2, float* __restrict__ F2) {
  __shared__ float sp1[4][16], sp2[4][16];
  const int t = threadIdx.x, lane = t & 63, w = t >> 6;
  const int il = lane & 15, kg = lane >> 4;
  const int ibase = blockIdx.x * 16;
  const int d = w * 16 + il;
  const float* frow = feat + (size_t)(ibase + il) * DD + kg * 8;
  const ushort* wrow = WT + (size_t)d * DD + kg * 8;
  f32x4 acc = {0.f, 0.f, 0.f, 0.f};
#pragma unroll
  for (int k0 = 0; k0 < DD; k0 += 32) {
    const float4 fa = *(const float4*)(frow + k0);
    const float4 fb = *(const float4*)(frow + k0 + 4);
    bf16x8 av;
    av[0] = f2bf(fa.x); av[1] = f2bf(fa.y); av[2] = f2bf(fa.z); av[3] = f2bf(fa.w);
    av[4] = f2bf(fb.x); av[5] = f2bf(fb.y); av[6] = f2bf(fb.z); av[7] = f2bf(fb.w);
    const bf16x8 bv = *(const bf16x8*)(wrow + k0);
    acc = __builtin_amdgcn_mfma_f32_16x16x32_bf16(av, bv, acc, 0, 0, 0);
  }
  ushort4 hv;
  hv.x = f2bf(acc[0]);
  hv.y = f2bf(acc[1]);
  hv.z = f2bf(acc[2]);
  hv.w = f2bf(acc[3]);
  {
    const int i0q = ibase + kg * 4;  // 4-aligned "j" index of hTf
    const size_t hb = ((size_t)(w * 256 + (i0q >> 5)) * 64 +
                       ((i0q >> 3) & 3) * 16 + il) * 8 + (i0q & 7);
    *(ushort4*)(hTf + hb) = hv;
  }
  const float a1v = a[d], a2v = a[FF + d];
#pragma unroll
  for (int r = 0; r < 4; ++r) {
    float v1 = acc[r] * a1v;
    float v2 = acc[r] * a2v;
#pragma unroll
    for (int m = 1; m <= 8; m <<= 1) {
      v1 += __shfl_xor(v1, m);
      v2 += __shfl_xor(v2, m);
    }
    if (il == 0) {
      sp1[w][kg * 4 + r] = v1;
      sp2[w][kg * 4 + r] = v2;
    }
  }
  __syncthreads();
  if (t < 16) {
    const float s1 = sp1[0][t] + sp1[1][t] + sp1[2][t] + sp1[3][t];
    const float s2 = sp2[0][t] + sp2[1][t] + sp2[2][t] + sp2[3][t];
    E1[ibase + t] = __expf(s1);
    F1[ibase + t] = __expf(0.2f * s1);
    E2[ibase + t] = __expf(s2);
    F2[ibase + t] = __expf(0.2f * s2);
  }
}

// ---------------------------------------------------------------------------
// k_attn: fused mask+softmax+PV+ELU, writes FINAL output (no partial bufs).
// Block = 16 rows x 8 waves; wave w owns j-window [w*1024,(w+1)*1024).
// Phase A (per 128-j tile): adj read coalesced (2 rows x 512B per instr),
//   p = adj ? (E1*E2 >= 1 ? E1*E2 : F1*F2) : 0   [= exp(lrelu(s1+s2)),
//   factorized -- no exp/lrelu in the loop; bound cancels in normalization],
//   bf16-packed into XOR-swizzled wave-private LDS tile. No barriers.
// Phase B: ds_read_b128 B-frags (swizzle-matched), hTf A-frags coalesced,
//   4 MFMA + 1 ones-MFMA (l-sum from the SAME bf16 p values).
// Epilogue: per-wave tr tile + l to LDS, __syncthreads, 8-way combine,
//   normalize, ELU, coalesced store.
// ---------------------------------------------------------------------------
__global__ __launch_bounds__(512) void k_attn(
    const int* __restrict__ adj, const ushort* __restrict__ hTf,
    const float* __restrict__ E1g, const float* __restrict__ F1g,
    const float* __restrict__ E2g, const float* __restrict__ F2g,
    float* __restrict__ out) {
  __shared__ __align__(16) char smem[WPB][4480];
  __shared__ float lw[WPB][16];
  const int t = threadIdx.x;
  const int lane = t & 63, w = t >> 6;
  const int il = lane & 15, kg = lane >> 4;
  const int rbase = blockIdx.x * ROWS;
  const int jwin0 = w * JW;
  char* const smemw = smem[w];
  const int arow = lane >> 5;        // which of 2 rows per rep
  const int acol = (lane & 31) * 4;  // 4 consecutive j per lane

  float e1p[8], f1p[8];
#pragma unroll
  for (int rep = 0; rep < 8; ++rep) {
    const int r = rbase + rep * 2 + arow;
    e1p[rep] = E1g[r];
    f1p[rep] = F1g[r];
  }
  bf16x8 ones;
#pragma unroll
  for (int e = 0; e < 8; ++e) ones[e] = (short)0x3F80;  // bf16 1.0

  f32x4 acc[4] = {{0,0,0,0},{0,0,0,0},{0,0,0,0},{0,0,0,0}};
  f32x4 accl = {0.f, 0.f, 0.f, 0.f};

  for (int tile = 0; tile < NT; ++tile) {
    const int jt = jwin0 + tile * CT;
    // ---- Phase A ----
    const float4 e2v = *(const float4*)(E2g + jt + acol);
    const float4 f2v = *(const float4*)(F2g + jt + acol);
#pragma unroll
    for (int rep = 0; rep < 8; ++rep) {
      const int r = rep * 2 + arow;
      const int4 av = *(const int4*)(adj + (size_t)(rbase + r) * NN + jt + acol);
      const float e1 = e1p[rep], f1 = f1p[rep];
      float m0 = e1 * e2v.x, m1 = e1 * e2v.y, m2 = e1 * e2v.z, m3 = e1 * e2v.w;
      float p0 = m0 >= 1.f ? m0 : f1 * f2v.x;
      float p1 = m1 >= 1.f ? m1 : f1 * f2v.y;
      float p2 = m2 >= 1.f ? m2 : f1 * f2v.z;
      float p3 = m3 >= 1.f ? m3 : f1 * f2v.w;
      ushort4 pk;
      pk.x = av.x ? f2bf(p0) : (ushort)0;
      pk.y = av.y ? f2bf(p1) : (ushort)0;
      pk.z = av.z ? f2bf(p2) : (ushort)0;
      pk.w = av.w ? f2bf(p3) : (ushort)0;
      const int swz = r * 256 + ((acol * 2) ^ ((r & 7) << 4));
      *(ushort4*)(smemw + swz) = pk;
    }
    // ---- Phase B (same-wave LDS write->read; in-order DS, no barrier) ----
#pragma unroll
    for (int sb = 0; sb < 4; ++sb) {
      const int coff = (sb * 32 + kg * 8) * 2;
      const bf16x8 pb = *(const bf16x8*)(smemw + il * 256 + (coff ^ ((il & 7) << 4)));
      const int j32 = (jt >> 5) + sb;
      accl = __builtin_amdgcn_mfma_f32_16x16x32_bf16(ones, pb, accl, 0, 0, 0);
#pragma unroll
      for (int f = 0; f < 4; ++f) {
        const bf16x8 hv =
            *(const bf16x8*)(hTf + ((size_t)(f * 256 + j32) * 64 + lane) * 8);
        acc[f] = __builtin_amdgcn_mfma_f32_16x16x32_bf16(hv, pb, acc[f], 0, 0, 0);
      }
    }
  }
  // per-wave results to LDS: lane holds i = rbase+il (col), d = f*16+kg*4+r
  float (*tr)[65] = (float(*)[65])smemw;
#pragma unroll
  for (int f = 0; f < 4; ++f)
#pragma unroll
    for (int r = 0; r < 4; ++r) tr[il][f * 16 + kg * 4 + r] = acc[f][r];
  if (lane < 16) lw[w][il] = accl[0];  // l_i partial (replicated across regs/kg)
  __syncthreads();
  // 8-way combine + normalize + ELU, coalesced
#pragma unroll
  for (int k = 0; k < (ROWS * FF) / 512; ++k) {
    const int idx = t + k * 512;
    const int row = idx >> 6, d = idx & 63;
    float s = 0.f, L = 0.f;
#pragma unroll
    for (int ww = 0; ww < WPB; ++ww) {
      s += ((float(*)[65])smem[ww])[row][d];
      L += lw[ww][row];
    }
    const float x = s / fmaxf(L, 1e-30f);
    out[(size_t)(rbase + row) * FF + d] = x > 0.f ? x : expm1f(x);
  }
}

extern "C" void kernel_launch(void* const* d_in, const int* in_sizes, int n_in,
                              void* d_out, int out_size, void* d_ws, size_t ws_size,
                              hipStream_t stream) {
  const float* feat = (const float*)d_in[0];
  const int* adj = (const int*)d_in[1];
  const float* W = (const float*)d_in[2];
  const float* a = (const float*)d_in[3];
  float* out = (float*)d_out;

  ushort* hTf = (ushort*)d_ws;                      // 64*8192 bf16 = 1 MB
  ushort* WT = hTf + (size_t)FF * NN;               // 64*256 bf16 = 32 KB
  float* E1 = (float*)(WT + (size_t)FF * DD);       // 8192 f32
  float* F1 = E1 + NN;
  float* E2 = F1 + NN;
  float* F2 = E2 + NN;

  hipLaunchKernelGGL(k_pre, dim3(DD * FF / 1024), dim3(256), 0, stream, W, WT);
  hipLaunchKernelGGL(k_h, dim3(NN / 16), dim3(256), 0, stream, feat, WT, a, hTf,
                     E1, F1, E2, F2);
  hipLaunchKernelGGL(k_attn, dim3(NN / ROWS), dim3(512), 0, stream,
                     adj, hTf, E1, F1, E2, F2, out);
}